// Round 1
// baseline (292.288 us; speedup 1.0000x reference)
//
#include <hip/hip_runtime.h>
#include <stdint.h>

// MultiHeadAttentionProj: B=4, N=2048, D=512, H=8, HD=64
// cvtW -> maskprep -> GEMM QKV (A=f32 q, converted in staging; Q scaled 0.125*log2e)
// -> flash attn (BM=64, 4 waves, 1024 blocks = 4/CU resident, S^T form,
//    exp2 softmax with bias/mask folded into MFMA C-init, row-sum via MFMA)
// -> GEMM out. fp32 accumulation.

typedef __attribute__((ext_vector_type(8))) short short8;
typedef __attribute__((ext_vector_type(4))) short short4v;
typedef __attribute__((ext_vector_type(4))) float f32x4;

#define DEV static __device__ __forceinline__

constexpr int Bc = 4, Nc = 2048, Dc = 512, Hc = 8, HDc = 64;
constexpr int Mc = Bc * Nc;        // 8192 rows
constexpr int QKVNc = 3 * Dc;      // 1536
constexpr float L2E = 1.44269504f;

DEV short bf16cast(float f) {      // f32 -> bf16 bits (RNE via HW cvt)
  return (short)__builtin_bit_cast(unsigned short, (__bf16)f);
}
DEV unsigned cvt_pk_bf16(float a, float b) {  // a->low16, b->high16 (RNE)
  unsigned short lb = __builtin_bit_cast(unsigned short, (__bf16)a);
  unsigned short hb = __builtin_bit_cast(unsigned short, (__bf16)b);
  return (unsigned)lb | ((unsigned)hb << 16);
}
DEV unsigned pack_shorts(short a, short b) {
  return (unsigned)(unsigned short)a | ((unsigned)(unsigned short)b << 16);
}
DEV short8 cvt8(float4 a, float4 b) {   // 8 f32 -> short8 bf16
  union { short8 s; uint4 u; } r;
  r.u.x = cvt_pk_bf16(a.x, a.y); r.u.y = cvt_pk_bf16(a.z, a.w);
  r.u.z = cvt_pk_bf16(b.x, b.y); r.u.w = cvt_pk_bf16(b.z, b.w);
  return r.s;
}
DEV float fast_exp2(float x) {
#if __has_builtin(__builtin_amdgcn_exp2f)
  return __builtin_amdgcn_exp2f(x);
#else
  return exp2f(x);
#endif
}

// One launch converts Wq,Wk,Wv -> Wqkv (concat) and Wo -> Wob.
__global__ void cvtw_kernel(const float* __restrict__ Wq, const float* __restrict__ Wk,
                            const float* __restrict__ Wv, const float* __restrict__ Wo,
                            short* __restrict__ Wqkv, short* __restrict__ Wob) {
  int which = blockIdx.x >> 8;                       // 4 x 256 blocks
  int j = (blockIdx.x & 255) * 256 + threadIdx.x;    // float4 index < 65536
  const float* src = which == 0 ? Wq : which == 1 ? Wk : which == 2 ? Wv : Wo;
  short* dst = (which == 3) ? Wob : Wqkv + which * (Dc * Dc);
  float4 v = ((const float4*)src)[j];
  short4v o = { bf16cast(v.x), bf16cast(v.y), bf16cast(v.z), bf16cast(v.w) };
  ((short4v*)dst)[j] = o;
}

// Single block: detect mask dtype (int32 vs bool bytes), then convert to
// additive floats. int32 0/1 LE has bytes 1..3 of every word zero.
__global__ void maskprep_kernel(const void* __restrict__ mask, float* __restrict__ mf) {
  __shared__ int flag;
  if (threadIdx.x == 0) flag = 0;
  __syncthreads();
  const uchar4* m4 = (const uchar4*)mask;
  int acc = 0;
  for (int i = threadIdx.x; i < 2048; i += 1024) {
    uchar4 v = m4[i];
    acc |= (int)v.y | (int)v.z | (int)v.w;
  }
  if (acc) atomicOr(&flag, 1);
  __syncthreads();
  int isbyte = flag;
  for (int i = threadIdx.x; i < Bc * Nc; i += 1024) {
    int v = isbyte ? (int)((const unsigned char*)mask)[i] : ((const int*)mask)[i];
    mf[i] = v ? -1e30f : 0.0f;
  }
}

// C[M][N] = sum_k A[m][k]*Bm[n][k]. 128x128 tile, BK=64, rows padded to 72
// shorts; reg-prefetch pipeline. A_F32: A is f32, converted during staging.
template<bool A_F32, bool OUT_F32>
__global__ __launch_bounds__(256, 2) void gemm_bt(const void* __restrict__ Av,
                                                  const short* __restrict__ Bm,
                                                  void* __restrict__ Cv,
                                                  int M, int N, int K,
                                                  int qcols, float cscale) {
  __shared__ __align__(16) short At[128 * 72];
  __shared__ __align__(16) short Bt[128 * 72];
  const int tid = threadIdx.x, lane = tid & 63, wv = tid >> 6;
  const int quad = lane >> 4, l16 = lane & 15;
  const int mbase = blockIdx.y * 128, nbase = blockIdx.x * 128;
  const int wr = (wv >> 1) * 64, wc = (wv & 1) * 64;
  const float scale = (nbase < qcols) ? cscale : 1.0f;
  f32x4 acc[4][4] = {};
  float4 apf[4][2]; short8 aph[4], bpre[4];
#pragma unroll
  for (int i = 0; i < 4; i++) {                 // preload k0=0
    int flat = i * 256 + tid, row = flat >> 3, ch8 = (flat & 7) * 8;
    if (A_F32) {
      const float* Af = (const float*)Av;
      apf[i][0] = *(const float4*)&Af[(size_t)(mbase + row) * K + ch8];
      apf[i][1] = *(const float4*)&Af[(size_t)(mbase + row) * K + ch8 + 4];
    } else {
      aph[i] = *(const short8*)&((const short*)Av)[(size_t)(mbase + row) * K + ch8];
    }
    bpre[i] = *(const short8*)&Bm[(size_t)(nbase + row) * K + ch8];
  }
  for (int k0 = 0; k0 < K; k0 += 64) {
    __syncthreads();
#pragma unroll
    for (int i = 0; i < 4; i++) {
      int flat = i * 256 + tid, row = flat >> 3, ch8 = (flat & 7) * 8;
      *(short8*)&At[row * 72 + ch8] = A_F32 ? cvt8(apf[i][0], apf[i][1]) : aph[i];
      *(short8*)&Bt[row * 72 + ch8] = bpre[i];
    }
    if (k0 + 64 < K) {
#pragma unroll
      for (int i = 0; i < 4; i++) {             // prefetch next tile
        int flat = i * 256 + tid, row = flat >> 3, ch8 = (flat & 7) * 8;
        if (A_F32) {
          const float* Af = (const float*)Av;
          apf[i][0] = *(const float4*)&Af[(size_t)(mbase + row) * K + k0 + 64 + ch8];
          apf[i][1] = *(const float4*)&Af[(size_t)(mbase + row) * K + k0 + 64 + ch8 + 4];
        } else {
          aph[i] = *(const short8*)&((const short*)Av)[(size_t)(mbase + row) * K + k0 + 64 + ch8];
        }
        bpre[i] = *(const short8*)&Bm[(size_t)(nbase + row) * K + k0 + 64 + ch8];
      }
    }
    __syncthreads();
#pragma unroll
    for (int s = 0; s < 2; s++) {
      short8 af[4], bf[4];
#pragma unroll
      for (int t = 0; t < 4; t++) {
        af[t] = *(short8*)&At[(wr + t * 16 + l16) * 72 + quad * 8 + s * 32];
        bf[t] = *(short8*)&Bt[(wc + t * 16 + l16) * 72 + quad * 8 + s * 32];
      }
#pragma unroll
      for (int mt = 0; mt < 4; mt++)
#pragma unroll
        for (int nt = 0; nt < 4; nt++)
          acc[mt][nt] = __builtin_amdgcn_mfma_f32_16x16x32_bf16(af[mt], bf[nt], acc[mt][nt], 0, 0, 0);
    }
  }
#pragma unroll
  for (int mt = 0; mt < 4; mt++)
#pragma unroll
    for (int nt = 0; nt < 4; nt++)
#pragma unroll
      for (int r = 0; r < 4; r++) {             // C/D: row=quad*4+r, col=l16
        int row = mbase + wr + mt * 16 + quad * 4 + r;
        int col = nbase + wc + nt * 16 + l16;
        float v = acc[mt][nt][r] * scale;
        if (OUT_F32) ((float*)Cv)[(size_t)row * N + col] = v;
        else         ((short*)Cv)[(size_t)row * N + col] = bf16cast(v);
      }
}

// Flash attention, S^T form. BM=64 q-rows, 256 threads (4 waves x 16 q-rows),
// 64-key tiles, register-prefetch of K/V/bias, mask in LDS.
// Softmax: C-init = bias*log2e + mask  (Q pre-scaled 0.125*log2e)  -> p = exp2(S')
// Row-sum via extra MFMA against all-ones B (sumacc rows line up with oacc rows).
__global__ __launch_bounds__(256, 4) void attn_kernel(const short* __restrict__ QKV,
                                                      const float* __restrict__ bias,
                                                      const float* __restrict__ maskf,
                                                      short* __restrict__ Aout) {
  __shared__ __align__(16) short Kt[64 * 72];        // [key][hd]
  __shared__ __align__(16) short Vt[64 * 72];        // [hd][key]
  __shared__ __align__(16) short Pt[4][16 * 72];     // per-wave P[q][key]
  __shared__ __align__(16) float mlds[Nc];
  const int tid = threadIdx.x, lane = tid & 63, wv = tid >> 6;   // wv 0..3
  const int quad = lane >> 4, l16 = lane & 15;
  const int qt = blockIdx.x & 31, h = (blockIdx.x >> 5) & 7, b = (int)(blockIdx.x >> 8);
  const int qrow0 = qt * 64;
  const int qglob = qrow0 + wv * 16 + l16;
  const float* biasrow = bias + ((size_t)b * Nc + qglob) * Nc;
  const float* mfb = maskf + b * Nc;

  ((float4*)mlds)[tid]       = ((const float4*)mfb)[tid];        // 512 float4
  ((float4*)mlds)[tid + 256] = ((const float4*)mfb)[tid + 256];

  short8 qf[2];  // Q frag (pre-scaled 0.125*log2e): [q=l16][k=quad*8+j (+32s)]
  {
    const short* qp = QKV + (size_t)(b * Nc + qglob) * QKVNc + h * HDc + quad * 8;
    qf[0] = *(const short8*)qp;
    qf[1] = *(const short8*)(qp + 32);
  }

  const int vp = tid & 31, vq = tid >> 5;            // key-pair 0..31, hd-quad 0..7
  const int krow = tid >> 3, kch = (tid & 7) * 8;    // K staging: 2 rows/thread
  const short* Kbase = QKV + Dc + h * HDc;
  const short* Vbase = QKV + 2 * Dc + h * HDc;

  short8 kpre0, kpre1; short4v v0pre[2], v1pre[2]; float4 bpre[4];
  kpre0 = *(const short8*)&Kbase[(size_t)(b * Nc + krow) * QKVNc + kch];
  kpre1 = *(const short8*)&Kbase[(size_t)(b * Nc + krow + 32) * QKVNc + kch];
#pragma unroll
  for (int g = 0; g < 2; g++) {
    v0pre[g] = *(const short4v*)&Vbase[(size_t)(b * Nc + 2 * vp) * QKVNc + 4 * (vq + 8 * g)];
    v1pre[g] = *(const short4v*)&Vbase[(size_t)(b * Nc + 2 * vp + 1) * QKVNc + 4 * (vq + 8 * g)];
  }
#pragma unroll
  for (int t = 0; t < 4; t++) bpre[t] = *(const float4*)&biasrow[t * 16 + quad * 4];

  const short ONEB = (short)0x3F80;                  // bf16 1.0
  const short8 ones = { ONEB, ONEB, ONEB, ONEB, ONEB, ONEB, ONEB, ONEB };

  f32x4 oacc[4] = {};
  f32x4 sumacc = {};                                 // row-sum of P, rows = quad*4+r

  for (int kt = 0; kt < 32; kt++) {
    const int kb = kt * 64;
    const int kbn = ((kt + 1) & 31) * 64;            // next tile (wraps, in-bounds)
    __syncthreads();                                 // prev iter LDS reads done
    *(short8*)&Kt[krow * 72 + kch] = kpre0;          // K regs -> LDS (2 rows)
    *(short8*)&Kt[(krow + 32) * 72 + kch] = kpre1;
#pragma unroll
    for (int g = 0; g < 2; g++)                      // V regs -> LDS transposed (b32)
#pragma unroll
      for (int j = 0; j < 4; j++)
        *(unsigned*)&Vt[(4 * (vq + 8 * g) + j) * 72 + 2 * vp] = pack_shorts(v0pre[g][j], v1pre[g][j]);

    f32x4 sacc[4];                                   // C-init = bias*log2e + mask
#pragma unroll
    for (int t = 0; t < 4; t++) {
      float4 mv = *(const float4*)&mlds[kb + t * 16 + quad * 4];
      sacc[t][0] = __builtin_fmaf(bpre[t].x, L2E, mv.x);
      sacc[t][1] = __builtin_fmaf(bpre[t].y, L2E, mv.y);
      sacc[t][2] = __builtin_fmaf(bpre[t].z, L2E, mv.z);
      sacc[t][3] = __builtin_fmaf(bpre[t].w, L2E, mv.w);
    }

    kpre0 = *(const short8*)&Kbase[(size_t)(b * Nc + kbn + krow) * QKVNc + kch];
    kpre1 = *(const short8*)&Kbase[(size_t)(b * Nc + kbn + krow + 32) * QKVNc + kch];
#pragma unroll
    for (int g = 0; g < 2; g++) {
      v0pre[g] = *(const short4v*)&Vbase[(size_t)(b * Nc + kbn + 2 * vp) * QKVNc + 4 * (vq + 8 * g)];
      v1pre[g] = *(const short4v*)&Vbase[(size_t)(b * Nc + kbn + 2 * vp + 1) * QKVNc + 4 * (vq + 8 * g)];
    }
#pragma unroll
    for (int t = 0; t < 4; t++) bpre[t] = *(const float4*)&biasrow[kbn + t * 16 + quad * 4];
    __syncthreads();                                 // LDS tile kt ready

#pragma unroll
    for (int s = 0; s < 2; s++)                      // S^T[key=t*16+quad*4+r][q=l16]
#pragma unroll
      for (int t = 0; t < 4; t++) {                  // A=K frag (m=key), B=Q frag (n=q)
        short8 kf = *(short8*)&Kt[(t * 16 + l16) * 72 + quad * 8 + s * 32];
        sacc[t] = __builtin_amdgcn_mfma_f32_16x16x32_bf16(kf, qf[s], sacc[t], 0, 0, 0);
      }

#pragma unroll
    for (int t = 0; t < 4; t++) {                    // p = exp2(S'), pack to bf16
      float p0 = fast_exp2(sacc[t][0]);
      float p1 = fast_exp2(sacc[t][1]);
      float p2 = fast_exp2(sacc[t][2]);
      float p3 = fast_exp2(sacc[t][3]);
      uint2 u = { cvt_pk_bf16(p0, p1), cvt_pk_bf16(p2, p3) };
      *(uint2*)&Pt[wv][l16 * 72 + t * 16 + quad * 4] = u;   // P[q=l16][key]
    }

#pragma unroll
    for (int s = 0; s < 2; s++) {                    // O += P·V; rowsum += P·1
      short8 pf = *(short8*)&Pt[wv][l16 * 72 + quad * 8 + s * 32];
      sumacc = __builtin_amdgcn_mfma_f32_16x16x32_bf16(pf, ones, sumacc, 0, 0, 0);
#pragma unroll
      for (int t = 0; t < 4; t++) {
        short8 vf = *(short8*)&Vt[(t * 16 + l16) * 72 + quad * 8 + s * 32];
        oacc[t] = __builtin_amdgcn_mfma_f32_16x16x32_bf16(pf, vf, oacc[t], 0, 0, 0);
      }
    }
  }

#pragma unroll
  for (int r = 0; r < 4; r++) {                      // O: row q=quad*4+r, col hd=l16
    float inv = 1.0f / sumacc[r];                    // same rows as oacc -> no shuffle
    int row = b * Nc + qrow0 + wv * 16 + quad * 4 + r;
#pragma unroll
    for (int t = 0; t < 4; t++)
      Aout[(size_t)row * Dc + h * HDc + t * 16 + l16] = bf16cast(oacc[t][r] * inv);
  }
}

extern "C" void kernel_launch(void* const* d_in, const int* in_sizes, int n_in,
                              void* d_out, int out_size, void* d_ws, size_t ws_size,
                              hipStream_t stream) {
  const float* q    = (const float*)d_in[0];
  const void*  mask = d_in[1];
  const float* bias = (const float*)d_in[2];
  const float* Wq   = (const float*)d_in[3];
  const float* Wk   = (const float*)d_in[4];
  const float* Wv   = (const float*)d_in[5];
  const float* Wo   = (const float*)d_in[6];
  float* out = (float*)d_out;

  char* ws = (char*)d_ws;
  short* Wqkv = (short*)ws;  ws += (size_t)QKVNc * Dc * 2;
  short* Wob  = (short*)ws;  ws += (size_t)Dc * Dc * 2;
  float* mf   = (float*)ws;  ws += (size_t)Bc * Nc * 4;
  short* QKV  = (short*)ws;  ws += (size_t)Mc * QKVNc * 2;
  short* aout = (short*)ws;  ws += (size_t)Mc * Dc * 2;

  cvtw_kernel<<<dim3(1024), dim3(256), 0, stream>>>(Wq, Wk, Wv, Wo, Wqkv, Wob);
  maskprep_kernel<<<dim3(1), dim3(1024), 0, stream>>>(mask, mf);

  // Q pre-scaled by 0.125*log2e so attn can use exp2 directly.
  gemm_bt<true, false><<<dim3(QKVNc / 128, Mc / 128), dim3(256), 0, stream>>>(
      (const void*)q, Wqkv, (void*)QKV, Mc, QKVNc, Dc, Dc, 0.125f * L2E);
  attn_kernel<<<dim3(Bc * Hc * 32), dim3(256), 0, stream>>>(QKV, bias, mf, aout);
  gemm_bt<false, true><<<dim3(Dc / 128, Mc / 128), dim3(256), 0, stream>>>(
      (const void*)aout, Wob, (void*)out, Mc, Dc, Dc, 0, 1.0f);
}

// Round 2
// 277.589 us; speedup vs baseline: 1.0530x; 1.0530x over previous
//
#include <hip/hip_runtime.h>
#include <stdint.h>

// MultiHeadAttentionProj: B=4, N=2048, D=512, H=8, HD=64
// cvtW(+maskprep fused) -> GEMM QKV (A=f32 q, converted in staging; Q scaled
// 0.125*log2e) -> flash attn (BM=128, 8 waves, S^T form, exp2 softmax with
// bias/mask folded into MFMA C-init, row-sum via MFMA, single-barrier
// double-buffered K/V LDS, post-barrier prefetch issue) -> GEMM out.
// Both GEMM and attn use: write LDS -> ONE barrier -> issue next loads ->
// compute, so global prefetches age a full compute phase before the next
// barrier's vmcnt(0) drain (previous structure drained freshly-issued loads).

typedef __attribute__((ext_vector_type(8))) short short8;
typedef __attribute__((ext_vector_type(4))) short short4v;
typedef __attribute__((ext_vector_type(4))) float f32x4;

#define DEV static __device__ __forceinline__

constexpr int Bc = 4, Nc = 2048, Dc = 512, Hc = 8, HDc = 64;
constexpr int Mc = Bc * Nc;        // 8192 rows
constexpr int QKVNc = 3 * Dc;      // 1536
constexpr float L2E = 1.44269504f;

DEV short bf16cast(float f) {      // f32 -> bf16 bits (RNE via HW cvt)
  return (short)__builtin_bit_cast(unsigned short, (__bf16)f);
}
DEV unsigned cvt_pk_bf16(float a, float b) {  // a->low16, b->high16 (RNE)
  unsigned short lb = __builtin_bit_cast(unsigned short, (__bf16)a);
  unsigned short hb = __builtin_bit_cast(unsigned short, (__bf16)b);
  return (unsigned)lb | ((unsigned)hb << 16);
}
DEV unsigned pack_shorts(short a, short b) {
  return (unsigned)(unsigned short)a | ((unsigned)(unsigned short)b << 16);
}
DEV short8 cvt8(float4 a, float4 b) {   // 8 f32 -> short8 bf16
  union { short8 s; uint4 u; } r;
  r.u.x = cvt_pk_bf16(a.x, a.y); r.u.y = cvt_pk_bf16(a.z, a.w);
  r.u.z = cvt_pk_bf16(b.x, b.y); r.u.w = cvt_pk_bf16(b.z, b.w);
  return r.s;
}
DEV float fast_exp2(float x) {
#if __has_builtin(__builtin_amdgcn_exp2f)
  return __builtin_amdgcn_exp2f(x);
#else
  return exp2f(x);
#endif
}

// Blocks 0..1023: convert Wq,Wk,Wv -> Wqkv (concat) and Wo -> Wob.
// Block 1024: maskprep (detect mask dtype, convert to additive floats).
__global__ void cvtw_kernel(const float* __restrict__ Wq, const float* __restrict__ Wk,
                            const float* __restrict__ Wv, const float* __restrict__ Wo,
                            short* __restrict__ Wqkv, short* __restrict__ Wob,
                            const void* __restrict__ mask, float* __restrict__ mf) {
  if (blockIdx.x == 1024) {                          // fused maskprep, 256 threads
    __shared__ int flag;
    if (threadIdx.x == 0) flag = 0;
    __syncthreads();
    const uchar4* m4 = (const uchar4*)mask;
    int acc = 0;
    for (int i = threadIdx.x; i < 2048; i += 256) {
      uchar4 v = m4[i];
      acc |= (int)v.y | (int)v.z | (int)v.w;
    }
    if (acc) atomicOr(&flag, 1);
    __syncthreads();
    int isbyte = flag;                               // int32 0/1 has bytes 1..3 zero
    for (int i = threadIdx.x; i < Bc * Nc; i += 256) {
      int v = isbyte ? (int)((const unsigned char*)mask)[i] : ((const int*)mask)[i];
      mf[i] = v ? -1e30f : 0.0f;
    }
    return;
  }
  int which = blockIdx.x >> 8;                       // 4 x 256 blocks
  int j = (blockIdx.x & 255) * 256 + threadIdx.x;    // float4 index < 65536
  const float* src = which == 0 ? Wq : which == 1 ? Wk : which == 2 ? Wv : Wo;
  short* dst = (which == 3) ? Wob : Wqkv + which * (Dc * Dc);
  float4 v = ((const float4*)src)[j];
  short4v o = { bf16cast(v.x), bf16cast(v.y), bf16cast(v.z), bf16cast(v.w) };
  ((short4v*)dst)[j] = o;
}

// C[M][N] = sum_k A[m][k]*Bm[n][k]. 128x128 tile, BK=64, rows padded to 72
// shorts. Single-barrier double-buffered LDS; prefetch issued AFTER the
// barrier so the next barrier's vmcnt drain sees aged loads.
// A_F32: A is f32, converted during staging.
template<bool A_F32, bool OUT_F32>
__global__ __launch_bounds__(256, 2) void gemm_bt(const void* __restrict__ Av,
                                                  const short* __restrict__ Bm,
                                                  void* __restrict__ Cv,
                                                  int M, int N, int K,
                                                  int qcols, float cscale) {
  __shared__ __align__(16) short At[2][128 * 72];
  __shared__ __align__(16) short Bt[2][128 * 72];
  const int tid = threadIdx.x, lane = tid & 63, wv = tid >> 6;
  const int quad = lane >> 4, l16 = lane & 15;
  const int mbase = blockIdx.y * 128, nbase = blockIdx.x * 128;
  const int wr = (wv >> 1) * 64, wc = (wv & 1) * 64;
  const float scale = (nbase < qcols) ? cscale : 1.0f;
  f32x4 acc[4][4] = {};
  float4 apf[4][2]; short8 aph[4], bpre[4];
#pragma unroll
  for (int i = 0; i < 4; i++) {                 // preload k0=0
    int flat = i * 256 + tid, row = flat >> 3, ch8 = (flat & 7) * 8;
    if (A_F32) {
      const float* Af = (const float*)Av;
      apf[i][0] = *(const float4*)&Af[(size_t)(mbase + row) * K + ch8];
      apf[i][1] = *(const float4*)&Af[(size_t)(mbase + row) * K + ch8 + 4];
    } else {
      aph[i] = *(const short8*)&((const short*)Av)[(size_t)(mbase + row) * K + ch8];
    }
    bpre[i] = *(const short8*)&Bm[(size_t)(nbase + row) * K + ch8];
  }
  for (int k0 = 0; k0 < K; k0 += 64) {
    const int cur = (k0 >> 6) & 1;
    // W: regs -> LDS buf[cur]
#pragma unroll
    for (int i = 0; i < 4; i++) {
      int flat = i * 256 + tid, row = flat >> 3, ch8 = (flat & 7) * 8;
      *(short8*)&At[cur][row * 72 + ch8] = A_F32 ? cvt8(apf[i][0], apf[i][1]) : aph[i];
      *(short8*)&Bt[cur][row * 72 + ch8] = bpre[i];
    }
    __syncthreads();
    // L: issue next-tile loads (drained at NEXT iteration's barrier)
    if (k0 + 64 < K) {
#pragma unroll
      for (int i = 0; i < 4; i++) {
        int flat = i * 256 + tid, row = flat >> 3, ch8 = (flat & 7) * 8;
        if (A_F32) {
          const float* Af = (const float*)Av;
          apf[i][0] = *(const float4*)&Af[(size_t)(mbase + row) * K + k0 + 64 + ch8];
          apf[i][1] = *(const float4*)&Af[(size_t)(mbase + row) * K + k0 + 64 + ch8 + 4];
        } else {
          aph[i] = *(const short8*)&((const short*)Av)[(size_t)(mbase + row) * K + k0 + 64 + ch8];
        }
        bpre[i] = *(const short8*)&Bm[(size_t)(nbase + row) * K + k0 + 64 + ch8];
      }
    }
    // C: compute from buf[cur]
#pragma unroll
    for (int s = 0; s < 2; s++) {
      short8 af[4], bf[4];
#pragma unroll
      for (int t = 0; t < 4; t++) {
        af[t] = *(short8*)&At[cur][(wr + t * 16 + l16) * 72 + quad * 8 + s * 32];
        bf[t] = *(short8*)&Bt[cur][(wc + t * 16 + l16) * 72 + quad * 8 + s * 32];
      }
#pragma unroll
      for (int mt = 0; mt < 4; mt++)
#pragma unroll
        for (int nt = 0; nt < 4; nt++)
          acc[mt][nt] = __builtin_amdgcn_mfma_f32_16x16x32_bf16(af[mt], bf[nt], acc[mt][nt], 0, 0, 0);
    }
  }
#pragma unroll
  for (int mt = 0; mt < 4; mt++)
#pragma unroll
    for (int nt = 0; nt < 4; nt++)
#pragma unroll
      for (int r = 0; r < 4; r++) {             // C/D: row=quad*4+r, col=l16
        int row = mbase + wr + mt * 16 + quad * 4 + r;
        int col = nbase + wc + nt * 16 + l16;
        float v = acc[mt][nt][r] * scale;
        if (OUT_F32) ((float*)Cv)[(size_t)row * N + col] = v;
        else         ((short*)Cv)[(size_t)row * N + col] = bf16cast(v);
      }
}

// Flash attention, S^T form. BM=128 q-rows, 512 threads (8 waves x 16 q-rows),
// 64-key tiles. Single-barrier double-buffered K/V LDS; global prefetch issued
// after the barrier. Softmax: C-init = bias*log2e + mask (Q pre-scaled
// 0.125*log2e) -> p = exp2(S'). Row-sum via MFMA against all-ones B.
__global__ __launch_bounds__(512, 2) void attn_kernel(const short* __restrict__ QKV,
                                                      const float* __restrict__ bias,
                                                      const float* __restrict__ maskf,
                                                      short* __restrict__ Aout) {
  __shared__ __align__(16) short Kt[2][64 * 72];     // [key][hd], double-buffered
  __shared__ __align__(16) short Vt[2][64 * 72];     // [hd][key], double-buffered
  __shared__ __align__(16) short Pt[8][16 * 72];     // per-wave P[q][key]
  __shared__ __align__(16) float mlds[Nc];
  const int tid = threadIdx.x, lane = tid & 63, wv = tid >> 6;   // wv 0..7
  const int quad = lane >> 4, l16 = lane & 15;
  const int qt = blockIdx.x & 15, h = (blockIdx.x >> 4) & 7, b = (int)(blockIdx.x >> 7);
  const int qrow0 = qt * 128;
  const int qglob = qrow0 + wv * 16 + l16;
  const float* biasrow = bias + ((size_t)b * Nc + qglob) * Nc;
  const float* mfb = maskf + b * Nc;

  ((float4*)mlds)[tid] = ((const float4*)mfb)[tid];  // 512 float4 = 2048 floats

  short8 qf[2];  // Q frag (pre-scaled 0.125*log2e): [q=l16][k=quad*8+j (+32s)]
  {
    const short* qp = QKV + (size_t)(b * Nc + qglob) * QKVNc + h * HDc + quad * 8;
    qf[0] = *(const short8*)qp;
    qf[1] = *(const short8*)(qp + 32);
  }

  const int vp = tid & 31, vq = tid >> 5;            // key-pair 0..31, hd-quad 0..15
  const int krow = tid >> 3, kch = (tid & 7) * 8;    // K staging: 512 chunks, 1/thread
  const short* Kbase = QKV + Dc + h * HDc;
  const short* Vbase = QKV + 2 * Dc + h * HDc;

  short8 kpre; short4v v0pre, v1pre; float4 bpre[4];
  kpre  = *(const short8*)&Kbase[(size_t)(b * Nc + krow) * QKVNc + kch];
  v0pre = *(const short4v*)&Vbase[(size_t)(b * Nc + 2 * vp) * QKVNc + 4 * vq];
  v1pre = *(const short4v*)&Vbase[(size_t)(b * Nc + 2 * vp + 1) * QKVNc + 4 * vq];
#pragma unroll
  for (int t = 0; t < 4; t++) bpre[t] = *(const float4*)&biasrow[t * 16 + quad * 4];

  const short ONEB = (short)0x3F80;                  // bf16 1.0
  const short8 ones = { ONEB, ONEB, ONEB, ONEB, ONEB, ONEB, ONEB, ONEB };

  f32x4 oacc[4] = {};
  f32x4 sumacc = {};                                 // row-sum of P, rows = quad*4+r

  for (int kt = 0; kt < 32; kt++) {
    const int cur = kt & 1;
    const int kb = kt * 64;
    const int kbn = ((kt + 1) & 31) * 64;            // next tile (wraps, in-bounds)

    // W: regs -> LDS buf[cur]
    *(short8*)&Kt[cur][krow * 72 + kch] = kpre;
#pragma unroll
    for (int j = 0; j < 4; j++)                      // V -> LDS transposed (b32)
      *(unsigned*)&Vt[cur][(4 * vq + j) * 72 + 2 * vp] = pack_shorts(v0pre[j], v1pre[j]);

    __syncthreads();                                 // ONE barrier per tile

    // L: issue next-tile loads; drained at NEXT iteration's barrier
    float4 bcur[4];
#pragma unroll
    for (int t = 0; t < 4; t++) bcur[t] = bpre[t];
    kpre  = *(const short8*)&Kbase[(size_t)(b * Nc + kbn + krow) * QKVNc + kch];
    v0pre = *(const short4v*)&Vbase[(size_t)(b * Nc + kbn + 2 * vp) * QKVNc + 4 * vq];
    v1pre = *(const short4v*)&Vbase[(size_t)(b * Nc + kbn + 2 * vp + 1) * QKVNc + 4 * vq];
#pragma unroll
    for (int t = 0; t < 4; t++) bpre[t] = *(const float4*)&biasrow[kbn + t * 16 + quad * 4];

    // C: compute from buf[cur]
    f32x4 sacc[4];                                   // C-init = bias*log2e + mask
#pragma unroll
    for (int t = 0; t < 4; t++) {
      float4 mv = *(const float4*)&mlds[kb + t * 16 + quad * 4];
      sacc[t][0] = __builtin_fmaf(bcur[t].x, L2E, mv.x);
      sacc[t][1] = __builtin_fmaf(bcur[t].y, L2E, mv.y);
      sacc[t][2] = __builtin_fmaf(bcur[t].z, L2E, mv.z);
      sacc[t][3] = __builtin_fmaf(bcur[t].w, L2E, mv.w);
    }

#pragma unroll
    for (int s = 0; s < 2; s++)                      // S^T[key=t*16+quad*4+r][q=l16]
#pragma unroll
      for (int t = 0; t < 4; t++) {                  // A=K frag (m=key), B=Q frag (n=q)
        short8 kf = *(short8*)&Kt[cur][(t * 16 + l16) * 72 + quad * 8 + s * 32];
        sacc[t] = __builtin_amdgcn_mfma_f32_16x16x32_bf16(kf, qf[s], sacc[t], 0, 0, 0);
      }

#pragma unroll
    for (int t = 0; t < 4; t++) {                    // p = exp2(S'), pack to bf16
      float p0 = fast_exp2(sacc[t][0]);
      float p1 = fast_exp2(sacc[t][1]);
      float p2 = fast_exp2(sacc[t][2]);
      float p3 = fast_exp2(sacc[t][3]);
      uint2 u = { cvt_pk_bf16(p0, p1), cvt_pk_bf16(p2, p3) };
      *(uint2*)&Pt[wv][l16 * 72 + t * 16 + quad * 4] = u;   // P[q=l16][key]
    }

#pragma unroll
    for (int s = 0; s < 2; s++) {                    // O += P·V; rowsum += P·1
      short8 pf = *(short8*)&Pt[wv][l16 * 72 + quad * 8 + s * 32];
      sumacc = __builtin_amdgcn_mfma_f32_16x16x32_bf16(pf, ones, sumacc, 0, 0, 0);
#pragma unroll
      for (int t = 0; t < 4; t++) {
        short8 vf = *(short8*)&Vt[cur][(t * 16 + l16) * 72 + quad * 8 + s * 32];
        oacc[t] = __builtin_amdgcn_mfma_f32_16x16x32_bf16(pf, vf, oacc[t], 0, 0, 0);
      }
    }
  }

#pragma unroll
  for (int r = 0; r < 4; r++) {                      // O: row q=quad*4+r, col hd=l16
    float inv = 1.0f / sumacc[r];                    // same rows as oacc -> no shuffle
    int row = b * Nc + qrow0 + wv * 16 + quad * 4 + r;
#pragma unroll
    for (int t = 0; t < 4; t++)
      Aout[(size_t)row * Dc + h * HDc + t * 16 + l16] = bf16cast(oacc[t][r] * inv);
  }
}

extern "C" void kernel_launch(void* const* d_in, const int* in_sizes, int n_in,
                              void* d_out, int out_size, void* d_ws, size_t ws_size,
                              hipStream_t stream) {
  const float* q    = (const float*)d_in[0];
  const void*  mask = d_in[1];
  const float* bias = (const float*)d_in[2];
  const float* Wq   = (const float*)d_in[3];
  const float* Wk   = (const float*)d_in[4];
  const float* Wv   = (const float*)d_in[5];
  const float* Wo   = (const float*)d_in[6];
  float* out = (float*)d_out;

  char* ws = (char*)d_ws;
  short* Wqkv = (short*)ws;  ws += (size_t)QKVNc * Dc * 2;
  short* Wob  = (short*)ws;  ws += (size_t)Dc * Dc * 2;
  float* mf   = (float*)ws;  ws += (size_t)Bc * Nc * 4;
  short* QKV  = (short*)ws;  ws += (size_t)Mc * QKVNc * 2;
  short* aout = (short*)ws;  ws += (size_t)Mc * Dc * 2;

  cvtw_kernel<<<dim3(1025), dim3(256), 0, stream>>>(Wq, Wk, Wv, Wo, Wqkv, Wob, mask, mf);

  // Q pre-scaled by 0.125*log2e so attn can use exp2 directly.
  gemm_bt<true, false><<<dim3(QKVNc / 128, Mc / 128), dim3(256), 0, stream>>>(
      (const void*)q, Wqkv, (void*)QKV, Mc, QKVNc, Dc, Dc, 0.125f * L2E);
  attn_kernel<<<dim3(Bc * Hc * 16), dim3(512), 0, stream>>>(QKV, bias, mf, aout);
  gemm_bt<false, true><<<dim3(Dc / 128, Mc / 128), dim3(256), 0, stream>>>(
      (const void*)aout, Wob, (void*)out, Mc, Dc, Dc, 0, 1.0f);
}